// Round 1
// baseline (2116.169 us; speedup 1.0000x reference)
//
#include <hip/hip_runtime.h>
#include <hip/hip_bf16.h>
#include <cstdint>

#define M_TOT 16384
#define K_TOT 4096
#define N_TOT 4096
#define RNK   16
#define BM 128
#define BN 128
#define BK 32

using bf16x8 = __attribute__((ext_vector_type(8))) __bf16;
using f32x4  = __attribute__((ext_vector_type(4))) float;

__device__ __forceinline__ unsigned short f2bf(float f) {
  union { float f; unsigned u; } v; v.f = f;
  unsigned u = v.u;
  unsigned r = (u + 0x7fffu + ((u >> 16) & 1u)) >> 16;
  return (unsigned short)r;
}

// ---------------- f32 -> bf16 conversion (vectorized, grid-stride) ----------
__global__ void cvt_f32_bf16(const float* __restrict__ in,
                             unsigned short* __restrict__ out, int n4) {
  int i = blockIdx.x * blockDim.x + threadIdx.x;
  int stride = gridDim.x * blockDim.x;
  for (; i < n4; i += stride) {
    float4 v = reinterpret_cast<const float4*>(in)[i];
    ushort4 o;
    o.x = f2bf(v.x); o.y = f2bf(v.y); o.z = f2bf(v.z); o.w = f2bf(v.w);
    reinterpret_cast<ushort4*>(out)[i] = o;
  }
}

// ---------------- inter[m][r] = sum_k x[m][k] * la[e][r][k] (f32) -----------
// one block = 8 rows; t -> (r = t>>4, j = t&15); reduce over j via shfl_xor
__global__ __launch_bounds__(256) void inter_kernel(
    const float* __restrict__ x, const int* __restrict__ eid,
    const float* __restrict__ la, float* __restrict__ inter) {
  int row0 = blockIdx.x * 8;
  int e = eid[row0 >> 11];          // 2048 rows per batch
  int t = threadIdx.x;
  int r = t >> 4;
  int j = t & 15;
  const float* lar = la + ((size_t)e * RNK + r) * K_TOT;
  const float* xr  = x + (size_t)row0 * K_TOT;
  float acc[8] = {0.f,0.f,0.f,0.f,0.f,0.f,0.f,0.f};
  for (int c = 0; c < K_TOT / 16; ++c) {
    int k = c * 16 + j;
    float lav = lar[k];
#pragma unroll
    for (int q = 0; q < 8; ++q)
      acc[q] += xr[(size_t)q * K_TOT + k] * lav;
  }
#pragma unroll
  for (int q = 0; q < 8; ++q) {
    float a = acc[q];
    a += __shfl_xor(a, 1);
    a += __shfl_xor(a, 2);
    a += __shfl_xor(a, 4);
    a += __shfl_xor(a, 8);
    acc[q] = a;
  }
  if (j == 0) {
#pragma unroll
    for (int q = 0; q < 8; ++q)
      inter[(size_t)(row0 + q) * RNK + r] = acc[q];
  }
}

// ---------------- main GEMM: out = xb @ wb^T + bias + 2.0 * inter @ lb^T ----
#define GLD_LDS16(gsrc, ldst)                                                  \
  __builtin_amdgcn_global_load_lds(                                            \
      (__attribute__((address_space(1))) const void*)(gsrc),                   \
      (__attribute__((address_space(3))) void*)(ldst), 16, 0, 0)

__global__ __launch_bounds__(256) void gemm_kernel(
    const unsigned short* __restrict__ xb, const unsigned short* __restrict__ wb,
    const float* __restrict__ bias, const float* __restrict__ inter,
    const float* __restrict__ lb, const int* __restrict__ eid,
    float* __restrict__ out) {
  __shared__ unsigned char smem[16384];
  unsigned short (*As)[BK] = reinterpret_cast<unsigned short (*)[BK]>(smem);
  unsigned short (*Bs)[BK] = reinterpret_cast<unsigned short (*)[BK]>(smem + 8192);

  const int bn = blockIdx.x, bm = blockIdx.y;
  const int brow = bm * BM, bcol = bn * BN;
  const int t = threadIdx.x;
  const int w = t >> 6, l = t & 63;
  const int wr = w >> 1, wc = w & 1;      // 2x2 wave grid, each wave 64x64
  const int lr = l & 15;                  // fragment row/col selector
  const int lkb = (l >> 4) * 16;          // k byte offset within a tile row

  f32x4 acc[4][4];
#pragma unroll
  for (int i = 0; i < 4; ++i)
#pragma unroll
    for (int jj = 0; jj < 4; ++jj)
      acc[i][jj] = (f32x4){0.f, 0.f, 0.f, 0.f};

  // staging source: thread t loads 8 bf16 at (row = t>>2, col = (t&3)*8)
  const int srow = t >> 2;
  const int scol = (t & 3) * 8;
  const unsigned short* ga = xb + (size_t)(brow + srow) * K_TOT + scol;
  const unsigned short* gb = wb + (size_t)(bcol + srow) * K_TOT + scol;
  unsigned char* ldsA0 = smem + (w << 10);
  unsigned char* ldsA1 = smem + 4096 + (w << 10);
  unsigned char* ldsB0 = smem + 8192 + (w << 10);
  unsigned char* ldsB1 = smem + 12288 + (w << 10);

  for (int k0 = 0; k0 < K_TOT; k0 += BK) {
    GLD_LDS16(ga + k0,              ldsA0);
    GLD_LDS16(ga + 64 * K_TOT + k0, ldsA1);
    GLD_LDS16(gb + k0,              ldsB0);
    GLD_LDS16(gb + 64 * K_TOT + k0, ldsB1);
    __syncthreads();

    bf16x8 af[4], bfr[4];
#pragma unroll
    for (int mi = 0; mi < 4; ++mi)
      af[mi] = *reinterpret_cast<const bf16x8*>(
          reinterpret_cast<const unsigned char*>(&As[wr * 64 + mi * 16 + lr][0]) + lkb);
#pragma unroll
    for (int ni = 0; ni < 4; ++ni)
      bfr[ni] = *reinterpret_cast<const bf16x8*>(
          reinterpret_cast<const unsigned char*>(&Bs[wc * 64 + ni * 16 + lr][0]) + lkb);
#pragma unroll
    for (int mi = 0; mi < 4; ++mi)
#pragma unroll
      for (int ni = 0; ni < 4; ++ni)
        acc[mi][ni] = __builtin_amdgcn_mfma_f32_16x16x32_bf16(af[mi], bfr[ni],
                                                              acc[mi][ni], 0, 0, 0);
    __syncthreads();
  }

  // ---------------- epilogue: bias + 2.0 * inter @ lb^T ----------------
  const int e = eid[brow >> 11];
  float* interS = reinterpret_cast<float*>(smem);          // 128 x 16 f32
  float* lbS    = reinterpret_cast<float*>(smem + 8192);   // 128 x 16 f32
  const float* interG = inter + (size_t)brow * RNK;
  const float* lbG    = lb + ((size_t)e * N_TOT + bcol) * RNK;
#pragma unroll
  for (int q = 0; q < 8; ++q) {
    interS[t + 256 * q] = interG[t + 256 * q];
    lbS[t + 256 * q]    = lbG[t + 256 * q];
  }
  __syncthreads();

  float bv[4];
#pragma unroll
  for (int ni = 0; ni < 4; ++ni)
    bv[ni] = bias[bcol + wc * 64 + ni * 16 + lr];

#pragma unroll
  for (int mi = 0; mi < 4; ++mi) {
#pragma unroll
    for (int jj = 0; jj < 4; ++jj) {
      const int ml = wr * 64 + mi * 16 + (l >> 4) * 4 + jj;
      const float* iv = &interS[ml * RNK];
      const size_t orow = (size_t)(brow + ml) * N_TOT + bcol;
#pragma unroll
      for (int ni = 0; ni < 4; ++ni) {
        const int ol = wc * 64 + ni * 16 + lr;
        const float* lv = &lbS[ol * RNK];
        float d = 0.f;
#pragma unroll
        for (int r = 0; r < RNK; ++r) d += iv[r] * lv[r];
        out[orow + ol] = acc[mi][ni][jj] + bv[ni] + 2.0f * d;
      }
    }
  }
}

extern "C" void kernel_launch(void* const* d_in, const int* in_sizes, int n_in,
                              void* d_out, int out_size, void* d_ws, size_t ws_size,
                              hipStream_t stream) {
  const float* x    = (const float*)d_in[0];
  const int*   eid  = (const int*)d_in[1];
  const float* W    = (const float*)d_in[2];
  const float* bias = (const float*)d_in[3];
  const float* la   = (const float*)d_in[4];
  const float* lb   = (const float*)d_in[5];
  float* out = (float*)d_out;

  // workspace layout: xb (134MB) | wb (33.5MB) | inter (1MB)  => ~161MB
  unsigned short* xb = (unsigned short*)d_ws;
  unsigned short* wb = xb + (size_t)M_TOT * K_TOT;
  float* inter = (float*)(wb + (size_t)N_TOT * K_TOT);

  cvt_f32_bf16<<<2048, 256, 0, stream>>>(W, wb, (N_TOT * K_TOT) / 4);
  cvt_f32_bf16<<<2048, 256, 0, stream>>>(x, xb, (M_TOT * K_TOT) / 4);
  inter_kernel<<<M_TOT / 8, 256, 0, stream>>>(x, eid, la, inter);

  dim3 grid(N_TOT / BN, M_TOT / BM);
  gemm_kernel<<<grid, 256, 0, stream>>>(xb, wb, bias, inter, lb, eid, out);
}

// Round 2
// 1258.863 us; speedup vs baseline: 1.6810x; 1.6810x over previous
//
#include <hip/hip_runtime.h>
#include <hip/hip_bf16.h>
#include <cstdint>

#define M_TOT 16384
#define K_TOT 4096
#define N_TOT 4096
#define RNK   16
#define BM 256
#define BN 256
#define BK 64
#define NTK (K_TOT / BK)   // 64 K-tiles

using bf16x8 = __attribute__((ext_vector_type(8))) __bf16;
using f32x4  = __attribute__((ext_vector_type(4))) float;

__device__ __forceinline__ unsigned short f2bf(float f) {
  union { float f; unsigned u; } v; v.f = f;
  unsigned u = v.u;
  unsigned r = (u + 0x7fffu + ((u >> 16) & 1u)) >> 16;
  return (unsigned short)r;
}

// ---------------- f32 -> bf16 conversion (vectorized, grid-stride) ----------
__global__ void cvt_f32_bf16(const float* __restrict__ in,
                             unsigned short* __restrict__ out, int n4) {
  int i = blockIdx.x * blockDim.x + threadIdx.x;
  int stride = gridDim.x * blockDim.x;
  for (; i < n4; i += stride) {
    float4 v = reinterpret_cast<const float4*>(in)[i];
    ushort4 o;
    o.x = f2bf(v.x); o.y = f2bf(v.y); o.z = f2bf(v.z); o.w = f2bf(v.w);
    reinterpret_cast<ushort4*>(out)[i] = o;
  }
}

// ---------------- inter[m][r] = sum_k x[m][k] * la[e][r][k] (f32) -----------
__global__ __launch_bounds__(256) void inter_kernel(
    const float* __restrict__ x, const int* __restrict__ eid,
    const float* __restrict__ la, float* __restrict__ inter) {
  int row0 = blockIdx.x * 8;
  int e = eid[row0 >> 11];
  int t = threadIdx.x;
  int r = t >> 4;
  int j = t & 15;
  const float* lar = la + ((size_t)e * RNK + r) * K_TOT;
  const float* xr  = x + (size_t)row0 * K_TOT;
  float acc[8] = {0.f,0.f,0.f,0.f,0.f,0.f,0.f,0.f};
  for (int c = 0; c < K_TOT / 16; ++c) {
    int k = c * 16 + j;
    float lav = lar[k];
#pragma unroll
    for (int q = 0; q < 8; ++q)
      acc[q] += xr[(size_t)q * K_TOT + k] * lav;
  }
#pragma unroll
  for (int q = 0; q < 8; ++q) {
    float a = acc[q];
    a += __shfl_xor(a, 1);
    a += __shfl_xor(a, 2);
    a += __shfl_xor(a, 4);
    a += __shfl_xor(a, 8);
    acc[q] = a;
  }
  if (j == 0) {
#pragma unroll
    for (int q = 0; q < 8; ++q)
      inter[(size_t)(row0 + q) * RNK + r] = acc[q];
  }
}

// ---------------- 256x256 8-phase bf16 GEMM + fused LoRA epilogue -----------
#define GLD16(gsrc, ldst)                                                      \
  __builtin_amdgcn_global_load_lds(                                            \
      (__attribute__((address_space(1))) const void*)(gsrc),                   \
      (__attribute__((address_space(3))) void*)(ldst), 16, 0, 0)

#define FENCE() asm volatile("" ::: "memory")
#define BARRIER() do { FENCE(); __builtin_amdgcn_s_barrier(); FENCE(); } while (0)
#define LGKM0() do { asm volatile("s_waitcnt lgkmcnt(0)" ::: "memory");        \
                     __builtin_amdgcn_sched_barrier(0); } while (0)

// stage one K-half of A or B for tile T: 256 rows x 32 cols bf16 = 16KB, 2 GLD calls
#define STAGE(matB, kk, T) do {                                                \
  const int _b = (((T) & 1) << 16) + ((matB) << 15) + ((kk) << 14);            \
  const unsigned short* _g = (matB) ? gB : gA;                                 \
  const size_t _go = (size_t)(T) * BK + (size_t)(kk) * 32;                     \
  GLD16(_g + _go, smem + _b + ldsw);                                           \
  GLD16(_g + (size_t)128 * K_TOT + _go, smem + _b + 8192 + ldsw);              \
} while (0)

#define LD_A(mh, kk, bo) do {                                                  \
  _Pragma("unroll")                                                            \
  for (int i_ = 0; i_ < 4; ++i_)                                               \
    aF[i_] = *reinterpret_cast<const bf16x8*>(                                 \
        smem + (bo) + ((kk) << 14) + aofs + (((mh) * 4 + i_) << 10));          \
} while (0)

#define LD_B(kk, bo) do {                                                      \
  _Pragma("unroll")                                                            \
  for (int n_ = 0; n_ < 4; ++n_)                                               \
    bF[n_] = *reinterpret_cast<const bf16x8*>(                                 \
        smem + (bo) + 32768 + ((kk) << 14) + bofs + (n_ << 10));               \
} while (0)

#define MM_QUAD(mh) do {                                                       \
  __builtin_amdgcn_s_setprio(1);                                               \
  _Pragma("unroll")                                                            \
  for (int i_ = 0; i_ < 4; ++i_) {                                             \
    _Pragma("unroll")                                                          \
    for (int n_ = 0; n_ < 4; ++n_)                                             \
      acc[(mh) * 4 + i_][n_] = __builtin_amdgcn_mfma_f32_16x16x32_bf16(        \
          aF[i_], bF[n_], acc[(mh) * 4 + i_][n_], 0, 0, 0);                    \
  }                                                                            \
  __builtin_amdgcn_s_setprio(0);                                               \
  __builtin_amdgcn_sched_barrier(0);                                           \
} while (0)

__global__ __launch_bounds__(512, 2) void gemm_kernel(
    const unsigned short* __restrict__ xb, const unsigned short* __restrict__ wb,
    const float* __restrict__ bias, const float* __restrict__ inter,
    const float* __restrict__ lb, const int* __restrict__ eid,
    float* __restrict__ out) {
  __shared__ unsigned char smem[131072];

  const int bid = blockIdx.x;
  const int swz = (bid & 7) * 128 + (bid >> 3);   // 1024 wgs, bijective (1024%8==0)
  const int bm = swz >> 4, bn = swz & 15;         // 64 x 16 tiles
  const int brow = bm * BM, bcol = bn * BN;
  const int t = threadIdx.x;
  const int w = t >> 6, l = t & 63;
  const int wr = w >> 2, wc = w & 3;              // 2 x 4 wave grid, wave = 128x64 out
  const int lr = l & 15;

  // --- staging source (pre-swizzled: slot S fetches global slot S^(row&3)) ---
  const int srow = t >> 2;                        // 0..127 (call c adds +128)
  const int scol = ((t & 3) ^ (srow & 3)) << 3;   // element offset in 32-col half
  const unsigned short* gA = xb + (size_t)(brow + srow) * K_TOT + scol;
  const unsigned short* gB = wb + (size_t)(bcol + srow) * K_TOT + scol;
  const int ldsw = w << 10;                       // wave chunk within an 8KB call

  // --- ds_read bases (swizzled: slot = (l>>4) ^ (row&3), row&3 == lr&3) ---
  const int s4 = (((l >> 4) ^ (lr & 3)) << 4);
  const int aofs = wr * 8192 + lr * 64 + s4;      // + mi*1024 + kk*16384 + buf
  const int bofs = wc * 4096 + lr * 64 + s4;      // + ni*1024 + kk*16384 + buf + 32768

  f32x4 acc[8][4];
#pragma unroll
  for (int i = 0; i < 8; ++i)
#pragma unroll
    for (int n = 0; n < 4; ++n)
      acc[i][n] = (f32x4){0.f, 0.f, 0.f, 0.f};
  bf16x8 aF[4], bF[4];

  // --- prologue: tile0 all 4 halves + tile1 {B-k0, A-k0, B-k1} -------------
  STAGE(0, 0, 0); STAGE(1, 0, 0); STAGE(0, 1, 0); STAGE(1, 1, 0);
  STAGE(1, 0, 1); STAGE(0, 0, 1); STAGE(1, 1, 1);
  asm volatile("s_waitcnt vmcnt(6)" ::: "memory");
  BARRIER();

  for (int T = 0; T < NTK; ++T) {
    const int bo = (T & 1) << 16;
    // phase 0: Q(mh0, k0) ; stage A-k1(T+1) (other buf, long consumed)
    LD_A(0, 0, bo); LD_B(0, bo);
    if (T + 1 < NTK) STAGE(0, 1, T + 1);
    BARRIER(); LGKM0();
    MM_QUAD(0);
    BARRIER();
    // phase 1: Q(mh1, k0) ; stage B-k0(T+2) (region drained in phase 0)
    LD_A(1, 0, bo);
    if (T + 2 < NTK) STAGE(1, 0, T + 2);
    BARRIER(); LGKM0();
    MM_QUAD(1);
    BARRIER();
    // phase 2: Q(mh0, k1) ; stage A-k0(T+2) (region drained in phase 1)
    LD_A(0, 1, bo); LD_B(1, bo);
    if (T + 2 < NTK) STAGE(0, 0, T + 2);
    BARRIER(); LGKM0();
    MM_QUAD(0);
    BARRIER();
    // phase 3: Q(mh1, k1) ; stage B-k1(T+2) (region drained in phase 2)
    LD_A(1, 1, bo);
    if (T + 2 < NTK) STAGE(1, 1, T + 2);
    BARRIER(); LGKM0();
    MM_QUAD(1);
    if (T < NTK - 2) { asm volatile("s_waitcnt vmcnt(6)" ::: "memory"); }
    else             { asm volatile("s_waitcnt vmcnt(0)" ::: "memory"); }
    BARRIER();
  }

  // ---------------- epilogue: bias + 2.0 * inter @ lb^T ----------------
  __syncthreads();
  float* interS = reinterpret_cast<float*>(smem);           // 256 x 16 f32
  float* lbS    = reinterpret_cast<float*>(smem + 16384);   // 256 x 16 f32
  const int e = eid[brow >> 11];
  const float* interG = inter + (size_t)brow * RNK;
  const float* lbG    = lb + ((size_t)e * N_TOT + bcol) * RNK;
#pragma unroll
  for (int q = 0; q < 8; ++q) {
    interS[t + 512 * q] = interG[t + 512 * q];
    lbS[t + 512 * q]    = lbG[t + 512 * q];
  }
  __syncthreads();

  float bv[4];
#pragma unroll
  for (int n = 0; n < 4; ++n)
    bv[n] = bias[bcol + wc * 64 + n * 16 + lr];

#pragma unroll
  for (int mi = 0; mi < 8; ++mi) {
#pragma unroll
    for (int j = 0; j < 4; ++j) {
      const int ml = wr * 128 + mi * 16 + (l >> 4) * 4 + j;
      const float* iv = interS + ml * RNK;
      const size_t orow = (size_t)(brow + ml) * N_TOT + bcol;
#pragma unroll
      for (int n = 0; n < 4; ++n) {
        const int ol = wc * 64 + n * 16 + lr;
        const float* lv = lbS + ol * RNK;
        float d = 0.f;
#pragma unroll
        for (int r = 0; r < RNK; ++r) d += iv[r] * lv[r];
        out[orow + ol] = acc[mi][n][j] + bv[n] + 2.0f * d;
      }
    }
  }
}

extern "C" void kernel_launch(void* const* d_in, const int* in_sizes, int n_in,
                              void* d_out, int out_size, void* d_ws, size_t ws_size,
                              hipStream_t stream) {
  const float* x    = (const float*)d_in[0];
  const int*   eid  = (const int*)d_in[1];
  const float* W    = (const float*)d_in[2];
  const float* bias = (const float*)d_in[3];
  const float* la   = (const float*)d_in[4];
  const float* lb   = (const float*)d_in[5];
  float* out = (float*)d_out;

  // workspace layout: xb (134MB) | wb (33.5MB) | inter (1MB)
  unsigned short* xb = (unsigned short*)d_ws;
  unsigned short* wb = xb + (size_t)M_TOT * K_TOT;
  float* inter = (float*)(wb + (size_t)N_TOT * K_TOT);

  cvt_f32_bf16<<<2048, 256, 0, stream>>>(W, wb, (N_TOT * K_TOT) / 4);
  cvt_f32_bf16<<<2048, 256, 0, stream>>>(x, xb, (M_TOT * K_TOT) / 4);
  inter_kernel<<<M_TOT / 8, 256, 0, stream>>>(x, eid, la, inter);

  gemm_kernel<<<(M_TOT / BM) * (N_TOT / BN), 512, 0, stream>>>(
      xb, wb, bias, inter, lb, eid, out);
}

// Round 3
// 981.094 us; speedup vs baseline: 2.1569x; 1.2831x over previous
//
#include <hip/hip_runtime.h>
#include <hip/hip_bf16.h>
#include <cstdint>

#define M_TOT 16384
#define K_TOT 4096
#define N_TOT 4096
#define RNK   16
#define BM 256
#define BN 256
#define BK 64
#define NTK (K_TOT / BK)   // 64 K-tiles

using bf16x8 = __attribute__((ext_vector_type(8))) __bf16;
using f32x4  = __attribute__((ext_vector_type(4))) float;

__device__ __forceinline__ unsigned short f2bf(float f) {
  union { float f; unsigned u; } v; v.f = f;
  unsigned u = v.u;
  unsigned r = (u + 0x7fffu + ((u >> 16) & 1u)) >> 16;
  return (unsigned short)r;
}

// ---------------- f32 -> bf16 conversion (vectorized, grid-stride) ----------
__global__ void cvt_f32_bf16(const float* __restrict__ in,
                             unsigned short* __restrict__ out, int n4) {
  int i = blockIdx.x * blockDim.x + threadIdx.x;
  int stride = gridDim.x * blockDim.x;
  for (; i < n4; i += stride) {
    float4 v = reinterpret_cast<const float4*>(in)[i];
    ushort4 o;
    o.x = f2bf(v.x); o.y = f2bf(v.y); o.z = f2bf(v.z); o.w = f2bf(v.w);
    reinterpret_cast<ushort4*>(out)[i] = o;
  }
}

// ---------------- inter[m][r] = sum_k x[m][k] * la[e][r][k] (f32) -----------
__global__ __launch_bounds__(256) void inter_kernel(
    const float* __restrict__ x, const int* __restrict__ eid,
    const float* __restrict__ la, float* __restrict__ inter) {
  int row0 = blockIdx.x * 8;
  int e = eid[row0 >> 11];
  int t = threadIdx.x;
  int r = t >> 4;
  int j = t & 15;
  const float* lar = la + ((size_t)e * RNK + r) * K_TOT;
  const float* xr  = x + (size_t)row0 * K_TOT;
  float acc[8] = {0.f,0.f,0.f,0.f,0.f,0.f,0.f,0.f};
  for (int c = 0; c < K_TOT / 16; ++c) {
    int k = c * 16 + j;
    float lav = lar[k];
#pragma unroll
    for (int q = 0; q < 8; ++q)
      acc[q] += xr[(size_t)q * K_TOT + k] * lav;
  }
#pragma unroll
  for (int q = 0; q < 8; ++q) {
    float a = acc[q];
    a += __shfl_xor(a, 1);
    a += __shfl_xor(a, 2);
    a += __shfl_xor(a, 4);
    a += __shfl_xor(a, 8);
    acc[q] = a;
  }
  if (j == 0) {
#pragma unroll
    for (int q = 0; q < 8; ++q)
      inter[(size_t)(row0 + q) * RNK + r] = acc[q];
  }
}

// ---------------- 256x256 8-phase bf16 GEMM + fused LoRA epilogue -----------
#define GLD16(gsrc, ldst)                                                      \
  __builtin_amdgcn_global_load_lds(                                            \
      (__attribute__((address_space(1))) const void*)(gsrc),                   \
      (__attribute__((address_space(3))) void*)(ldst), 16, 0, 0)

#define FENCE() asm volatile("" ::: "memory")
#define BARRIER() do { FENCE(); __builtin_amdgcn_s_barrier(); FENCE(); } while (0)
#define LGKM0() do { asm volatile("s_waitcnt lgkmcnt(0)" ::: "memory");        \
                     __builtin_amdgcn_sched_barrier(0); } while (0)

// stage one K-half of A or B for tile T: 256 rows x 32 cols bf16 = 16KB, 2 GLD calls
#define STAGE(matB, kk, T) do {                                                \
  const int _b = (((T) & 1) << 16) + ((matB) << 15) + ((kk) << 14);            \
  const unsigned short* _g = (matB) ? gB : gA;                                 \
  const size_t _go = (size_t)(T) * BK + (size_t)(kk) * 32;                     \
  GLD16(_g + _go, smem + _b + ldsw);                                           \
  GLD16(_g + (size_t)128 * K_TOT + _go, smem + _b + 8192 + ldsw);              \
} while (0)

#define LD_A(mh, kk, bo) do {                                                  \
  _Pragma("unroll")                                                            \
  for (int i_ = 0; i_ < 4; ++i_)                                               \
    aF[i_] = *reinterpret_cast<const bf16x8*>(                                 \
        smem + (bo) + ((kk) << 14) + aofs + (((mh) * 4 + i_) << 10));          \
} while (0)

#define LD_B(kk, bo) do {                                                      \
  _Pragma("unroll")                                                            \
  for (int n_ = 0; n_ < 4; ++n_)                                               \
    bF[n_] = *reinterpret_cast<const bf16x8*>(                                 \
        smem + (bo) + 32768 + ((kk) << 14) + bofs + (n_ << 10));               \
} while (0)

#define MM_QUAD(mh) do {                                                       \
  __builtin_amdgcn_s_setprio(1);                                               \
  _Pragma("unroll")                                                            \
  for (int i_ = 0; i_ < 4; ++i_) {                                             \
    _Pragma("unroll")                                                          \
    for (int n_ = 0; n_ < 4; ++n_)                                             \
      acc[(mh) * 4 + i_][n_] = __builtin_amdgcn_mfma_f32_16x16x32_bf16(        \
          aF[i_], bF[n_], acc[(mh) * 4 + i_][n_], 0, 0, 0);                    \
  }                                                                            \
  __builtin_amdgcn_s_setprio(0);                                               \
  __builtin_amdgcn_sched_barrier(0);                                           \
} while (0)

__global__ __launch_bounds__(512, 2) void gemm_kernel(
    const unsigned short* __restrict__ xb, const unsigned short* __restrict__ wb,
    const float* __restrict__ bias, const float* __restrict__ inter,
    const float* __restrict__ lb, const int* __restrict__ eid,
    float* __restrict__ out) {
  __shared__ unsigned char smem[131072];

  const int bid = blockIdx.x;
  const int swz = (bid & 7) * 128 + (bid >> 3);   // 1024 wgs, bijective (1024%8==0)
  const int bm = swz >> 4, bn = swz & 15;         // 64 x 16 tiles
  const int brow = bm * BM, bcol = bn * BN;
  const int t = threadIdx.x;
  const int w = t >> 6, l = t & 63;
  const int wr = w >> 2, wc = w & 3;              // 2 x 4 wave grid, wave = 128x64 out
  const int lr = l & 15;

  // --- staging source (pre-swizzled: LDS slot S of row r holds global slot
  //     S ^ ((r>>2)&3); bits 2-3 of row invariant mod 16 and mod 128) -------
  const int srow = t >> 2;                        // 0..127 (call c adds +128)
  const int scol = ((t & 3) ^ ((srow >> 2) & 3)) << 3;
  const unsigned short* gA = xb + (size_t)(brow + srow) * K_TOT + scol;
  const unsigned short* gB = wb + (size_t)(bcol + srow) * K_TOT + scol;
  const int ldsw = w << 10;                       // wave chunk within an 8KB call

  // --- ds_read: slot = (l>>4) ^ ((lr>>2)&3). Bank-start per quarter-wave:
  //     (lr&1)*16 + slot*4 -> 8 distinct starts x 2 lanes = 2-way = free ----
  const int s4 = (((l >> 4) ^ ((lr >> 2) & 3)) << 4);
  const int aofs = wr * 8192 + lr * 64 + s4;      // + mi*1024 + kk*16384 + buf
  const int bofs = wc * 4096 + lr * 64 + s4;      // + ni*1024 + kk*16384 + buf + 32768

  f32x4 acc[8][4];
#pragma unroll
  for (int i = 0; i < 8; ++i)
#pragma unroll
    for (int n = 0; n < 4; ++n)
      acc[i][n] = (f32x4){0.f, 0.f, 0.f, 0.f};
  bf16x8 aF[4], bF[4];

  // --- prologue: tile0 all 4 halves + tile1 {B-k0, A-k0, B-k1} -------------
  STAGE(0, 0, 0); STAGE(1, 0, 0); STAGE(0, 1, 0); STAGE(1, 1, 0);
  STAGE(1, 0, 1); STAGE(0, 0, 1); STAGE(1, 1, 1);
  asm volatile("s_waitcnt vmcnt(6)" ::: "memory");
  BARRIER();

  for (int T = 0; T < NTK; ++T) {
    const int bo = (T & 1) << 16;
    // phase 0: Q(mh0, k0) ; stage A-k1(T+1) (other buf, long consumed)
    LD_A(0, 0, bo); LD_B(0, bo);
    if (T + 1 < NTK) STAGE(0, 1, T + 1);
    BARRIER(); LGKM0();
    MM_QUAD(0);
    BARRIER();
    // phase 1: Q(mh1, k0) ; stage B-k0(T+2) (region drained in phase 0)
    LD_A(1, 0, bo);
    if (T + 2 < NTK) STAGE(1, 0, T + 2);
    BARRIER(); LGKM0();
    MM_QUAD(1);
    BARRIER();
    // phase 2: Q(mh0, k1) ; stage A-k0(T+2) (region drained in phase 1)
    LD_A(0, 1, bo); LD_B(1, bo);
    if (T + 2 < NTK) STAGE(0, 0, T + 2);
    BARRIER(); LGKM0();
    MM_QUAD(0);
    BARRIER();
    // phase 3: Q(mh1, k1) ; stage B-k1(T+2) (region drained in phase 2)
    LD_A(1, 1, bo);
    if (T + 2 < NTK) STAGE(1, 1, T + 2);
    BARRIER(); LGKM0();
    MM_QUAD(1);
    if (T < NTK - 2) { asm volatile("s_waitcnt vmcnt(6)" ::: "memory"); }
    else             { asm volatile("s_waitcnt vmcnt(0)" ::: "memory"); }
    BARRIER();
  }

  // ---------------- epilogue: bias + 2.0 * inter @ lb^T ----------------
  __syncthreads();
  float* interS = reinterpret_cast<float*>(smem);           // 256 x 16 f32 (broadcast reads)
  float* lbS    = reinterpret_cast<float*>(smem + 16384);   // 256 x 17 f32 (padded: lr-strided reads)
  const int e = eid[brow >> 11];
  const float* interG = inter + (size_t)brow * RNK;
  const float* lbG    = lb + ((size_t)e * N_TOT + bcol) * RNK;
#pragma unroll
  for (int q = 0; q < 8; ++q) {
    const int idx = t + 512 * q;
    interS[idx] = interG[idx];
    lbS[(idx >> 4) * 17 + (idx & 15)] = lbG[idx];
  }
  __syncthreads();

  float bv[4];
#pragma unroll
  for (int n = 0; n < 4; ++n)
    bv[n] = bias[bcol + wc * 64 + n * 16 + lr];

#pragma unroll
  for (int mi = 0; mi < 8; ++mi) {
#pragma unroll
    for (int j = 0; j < 4; ++j) {
      const int ml = wr * 128 + mi * 16 + (l >> 4) * 4 + j;
      const float* iv = interS + ml * RNK;
      const size_t orow = (size_t)(brow + ml) * N_TOT + bcol;
#pragma unroll
      for (int n = 0; n < 4; ++n) {
        const int ol = wc * 64 + n * 16 + lr;
        const float* lv = lbS + ol * 17;
        float d = 0.f;
#pragma unroll
        for (int r = 0; r < RNK; ++r) d += iv[r] * lv[r];
        out[orow + ol] = acc[mi][n][j] + bv[n] + 2.0f * d;
      }
    }
  }
}

extern "C" void kernel_launch(void* const* d_in, const int* in_sizes, int n_in,
                              void* d_out, int out_size, void* d_ws, size_t ws_size,
                              hipStream_t stream) {
  const float* x    = (const float*)d_in[0];
  const int*   eid  = (const int*)d_in[1];
  const float* W    = (const float*)d_in[2];
  const float* bias = (const float*)d_in[3];
  const float* la   = (const float*)d_in[4];
  const float* lb   = (const float*)d_in[5];
  float* out = (float*)d_out;

  // workspace layout: xb (134MB) | wb (33.5MB) | inter (1MB)
  unsigned short* xb = (unsigned short*)d_ws;
  unsigned short* wb = xb + (size_t)M_TOT * K_TOT;
  float* inter = (float*)(wb + (size_t)N_TOT * K_TOT);

  cvt_f32_bf16<<<2048, 256, 0, stream>>>(W, wb, (N_TOT * K_TOT) / 4);
  cvt_f32_bf16<<<2048, 256, 0, stream>>>(x, xb, (M_TOT * K_TOT) / 4);
  inter_kernel<<<M_TOT / 8, 256, 0, stream>>>(x, eid, la, inter);

  gemm_kernel<<<(M_TOT / BM) * (N_TOT / BN), 512, 0, stream>>>(
      xb, wb, bias, inter, lb, eid, out);
}